// Round 7
// baseline (172.755 us; speedup 1.0000x reference)
//
#include <hip/hip_runtime.h>
#include <hip/hip_bf16.h>
#include <math.h>

// Fully-fused TCN, R16: drop setprio + L4 d=16 fragment reuse + coalesced prep_w.
// R15 post-mortem: dead-rows paid sub-linearly (idle waves at barriers) and
// setprio is the known-negative lockstep regime (MfmaUtil dropped 25.4->23.1).
// Budget: LDS pipe ~64% (reads 70K cyc of 124K). Wave geometry (mt=2,nt=3) is
// read-minimal; remaining cut: at level 4 (d=16 = exactly one 16-row fragment
// block, same lane mapping), tap-k0's act fragment(nt) == tap-k1's
// fragment(nt-1). Cache k0's nt={1,2} frags in 32 VGPRs across the phase
// barrier -> k1 reads 4 instead of 12 act frags (both L4 convs).
// prep_w rewritten gather-style: each thread owns one contiguous short8
// output chunk (coalesced writes), inverting the fragment-major index.
// LDS = 2x(192x128) act + 2x(128x128) weights = 163840 B (160 KiB), 16 waves.

typedef __attribute__((ext_vector_type(8))) short short8;
typedef __attribute__((ext_vector_type(4))) short short4v;
typedef __attribute__((ext_vector_type(4))) float floatx4;

#define S_LEN 4096
#define ROWS 192                   // 64 halo + 128 outputs (12 row-blocks)
#define AREG (ROWS * 128)          // 24576 shorts per activation region
#define WBUF (128 * 128)           // 16384 shorts per weight buffer (32 KB)
#define LDS_BYTES ((2 * AREG + 2 * WBUF) * 2)   // 163840 B

// weight bank offsets (shorts) — each tap contiguous, fragment-major tiled
#define OFF_DS     0
#define OFF_L0C1_0 8192
#define OFF_L0C1_1 16384
#define OFF_L0C2_0 24576
#define OFF_L0C2_1 40960
#define OFF_C1B    57344      // + lvl*32768 ; tap1 at +16384
#define OFF_C2B    188416     // + lvl*32768 ; tap1 at +16384
#define WQ_TOTAL   319488

__device__ __forceinline__ float elu_f(float v) {
    return v > 0.0f ? v : (__expf(v) - 1.0f);
}
__device__ __forceinline__ short f2bs(float v) {
    __hip_bfloat16 h = __float2bfloat16(v);
    return *reinterpret_cast<short*>(&h);
}
__device__ __forceinline__ float bs2f(short s) {
    __hip_bfloat16 h = *reinterpret_cast<__hip_bfloat16*>(&s);
    return __bfloat162float(h);
}
__device__ __forceinline__ short4v pack4(const floatx4 v) {
    __hip_bfloat162 p0 = __float22bfloat162_rn(make_float2(v[0], v[1]));
    __hip_bfloat162 p1 = __float22bfloat162_rn(make_float2(v[2], v[3]));
    short4v r;
    r[0] = ((const short*)&p0)[0]; r[1] = ((const short*)&p0)[1];
    r[2] = ((const short*)&p1)[0]; r[3] = ((const short*)&p1)[1];
    return r;
}

// async 16B global->LDS copy (wave-uniform LDS base + lane*16 hardware rule)
__device__ __forceinline__ void gld_lds16(const void* g, void* l) {
    __builtin_amdgcn_global_load_lds(
        (const __attribute__((address_space(1))) void*)g,
        (__attribute__((address_space(3))) void*)l, 16, 0, 0);
}

// Issue async loads of one pre-tiled weight tap (NSH shorts) into LDS.
template<int NSH>
__device__ __forceinline__ void stage_async(short* __restrict__ lds,
                                            const short* __restrict__ src,
                                            int wave, int lane)
{
    constexpr int NI = (NSH * 2) / 16384;  // insts per wave (1 KB each, 16 waves)
    const char* g = (const char*)src + wave * 1024 + lane * 16;
    char* l = (char*)lds + wave * 1024;    // wave-uniform base
    #pragma unroll
    for (int i = 0; i < NI; ++i)
        gld_lds16(g + i * 16384, l + i * 16384);
}

// activation fragment offsets for one dilation (per nt), clamped at row 0
__device__ __forceinline__ void mkoff(int (&o)[3], int srow, int l16, int quad, int d) {
    #pragma unroll
    for (int nt = 0; nt < 3; ++nt) {
        int r = srow + nt * 16 + l16 - d;
        if (r < 0) r = 0;              // clamped rows never feed valid outputs
        o[nt] = (r >> 4) * 2048 + (r & 15) * 8 + quad * 128;
    }
}

// nt0 = first needed nt for this wave given a row floor (scalar math)
__device__ __forceinline__ int ntfloor(int minrow, int srow) {
    return (minrow > srow) ? ((minrow - srow + 15) >> 4) : 0;
}

// ---------------------------------------------------------------------------
// One tap's MFMAs: acc[mt][nt] += W[co][ci] * X[r - d][ci], nt >= nt0 only.
// ---------------------------------------------------------------------------
template<int KCH>
__device__ __forceinline__ void conv_tap(const short* __restrict__ Lin,
                                         const short* __restrict__ Lw,
                                         const int (&ao)[3], floatx4 (&acc)[2][3],
                                         const int nt0)
{
    if (nt0 >= 3) return;                  // whole wave idle this tap
    short8 wf[2][KCH];
    #pragma unroll
    for (int mt = 0; mt < 2; ++mt)
        #pragma unroll
        for (int kc = 0; kc < KCH; ++kc)
            wf[mt][kc] = *(const short8*)(Lw + mt * (KCH * 512) + kc * 512);
    #pragma unroll
    for (int nt = 0; nt < 3; ++nt) {
        if (nt < nt0) continue;
        const short* ab = Lin + ao[nt];
        #pragma unroll
        for (int kc = 0; kc < KCH; ++kc) {
            const short8 bf = *(const short8*)(ab + kc * 512);
            #pragma unroll
            for (int mt = 0; mt < 2; ++mt)
                acc[mt][nt] = __builtin_amdgcn_mfma_f32_16x16x32_bf16(wf[mt][kc], bf, acc[mt][nt], 0, 0, 0);
        }
    }
}

// d=16 specialization pair: k0 caches act frags nt={1,2}; k1 reuses them
// (frag(nt,k0 at d=16) == frag(nt-1, k1) — same lane, one block shift).
__device__ __forceinline__ void conv_tap_cache(const short* __restrict__ Lin,
    const short* __restrict__ Lw, const int (&ao)[3], floatx4 (&acc)[2][3],
    const int nt0, short8 (&cch)[2][4])
{
    if (nt0 >= 3) return;
    short8 wf[2][4];
    #pragma unroll
    for (int mt = 0; mt < 2; ++mt)
        #pragma unroll
        for (int kc = 0; kc < 4; ++kc)
            wf[mt][kc] = *(const short8*)(Lw + mt * 2048 + kc * 512);
    #pragma unroll
    for (int nt = 0; nt < 3; ++nt) {
        if (nt < nt0) continue;
        const short* ab = Lin + ao[nt];
        #pragma unroll
        for (int kc = 0; kc < 4; ++kc) {
            const short8 bf = *(const short8*)(ab + kc * 512);
            if (nt >= 1) cch[nt - 1][kc] = bf;
            #pragma unroll
            for (int mt = 0; mt < 2; ++mt)
                acc[mt][nt] = __builtin_amdgcn_mfma_f32_16x16x32_bf16(wf[mt][kc], bf, acc[mt][nt], 0, 0, 0);
        }
    }
}
__device__ __forceinline__ void conv_tap_reuse(const short* __restrict__ Lin,
    const short* __restrict__ Lw, const int (&ao)[3], floatx4 (&acc)[2][3],
    const int nt0, const short8 (&cch)[2][4])
{
    if (nt0 >= 3) return;
    short8 wf[2][4];
    #pragma unroll
    for (int mt = 0; mt < 2; ++mt)
        #pragma unroll
        for (int kc = 0; kc < 4; ++kc)
            wf[mt][kc] = *(const short8*)(Lw + mt * 2048 + kc * 512);
    #pragma unroll
    for (int nt = 0; nt < 3; ++nt) {
        if (nt < nt0) continue;
        #pragma unroll
        for (int kc = 0; kc < 4; ++kc) {
            const short8 bf = (nt < 2) ? cch[nt][kc]
                             : *(const short8*)(Lin + ao[2] + kc * 512);
            #pragma unroll
            for (int mt = 0; mt < 2; ++mt)
                acc[mt][nt] = __builtin_amdgcn_mfma_f32_16x16x32_bf16(wf[mt][kc], bf, acc[mt][nt], 0, 0, 0);
        }
    }
}

__device__ __forceinline__ void zero_acc(floatx4 (&acc)[2][3]) {
    #pragma unroll
    for (int mt = 0; mt < 2; ++mt)
        #pragma unroll
        for (int nt = 0; nt < 3; ++nt) acc[mt][nt] = {0.f, 0.f, 0.f, 0.f};
}

// ---------------------------------------------------------------------------
__global__ __launch_bounds__(1024, 4)
void tcn_fused(const float* __restrict__ x,     // fp32 [16,64,4096] channel-first
               const short* __restrict__ wq,
               const float* __restrict__ b1_0, const float* __restrict__ b2_0,
               const float* __restrict__ ds_b, const float* __restrict__ B1,
               const float* __restrict__ B2, float* __restrict__ out)
{
    extern __shared__ short L[];
    short* RA = L;                 // level io (X, then x1, ... in-place)
    short* RB = L + AREG;          // T scratch
    short* W0 = L + 2 * AREG;      // weight double-buffer
    short* W1 = L + 2 * AREG + WBUF;

    const int tid  = threadIdx.x;
    const int wave = __builtin_amdgcn_readfirstlane(tid >> 6);   // scalar
    const int lane = tid & 63;
    const int l16  = lane & 15, quad = lane >> 4;
    const int cobase = (wave & 3) * 32;    // 4 co-groups of 32   (scalar)
    const int srow   = (wave >> 2) * 48;   // 4 row-groups of 48  (scalar)
    const int s0  = blockIdx.x * 128;
    const int s0g = s0 - 64;
    const int b   = blockIdx.y;
    const bool zb = (s0 == 0);             // zero rows with global s < 0

    // per-wave constant addressing
    const int wqb2 = (cobase >> 4) * 1024 + quad * 128 + l16 * 8;  // KCH=2 base
    const int wqb4 = (cobase >> 4) * 2048 + quad * 128 + l16 * 8;  // KCH=4 base
    int aoff0[3], aoffd[3];
    mkoff(aoff0, srow, l16, quad, 0);
    int sb[3];
    #pragma unroll
    for (int nt = 0; nt < 3; ++nt) {
        const int sl = srow + nt * 16 + l16;
        sb[nt] = (sl >> 4) * 2048 + (sl & 15) * 8;
    }
    int ct[2];
    #pragma unroll
    for (int mt = 0; mt < 2; ++mt) {
        const int co4 = cobase + mt * 16 + quad * 4;
        ct[mt] = (co4 >> 5) * 512 + ((co4 >> 3) & 3) * 128 + (co4 & 7);
    }
    bool zr[3];
    #pragma unroll
    for (int nt = 0; nt < 3; ++nt) zr[nt] = zb && (srow + nt * 16 < 64);

    floatx4 acc[2][3];
    short4v x1keep[6];
    short4v dk[6];

    // ---- prologue: stage ds + c1_0k0 (both 16KB) into W0; stage X into RA
    stage_async<8192>(W0, wq + OFF_DS, wave, lane);
    stage_async<8192>(W0 + 8192, wq + OFF_L0C1_0, wave, lane);
    {
        const float* xp = x + (size_t)b * 64 * S_LEN;
        const int ci0 = wave * 4;
        const int cterm = (ci0 >> 5) * 512 + ((ci0 >> 3) & 3) * 128 + (ci0 & 7);
        #pragma unroll
        for (int h = 0; h < 3; ++h) {
            const int r = lane + h * 64;
            const int s = s0g + r;
            short4v pk;
            #pragma unroll
            for (int c4 = 0; c4 < 4; ++c4) {
                const float v = (s >= 0) ? xp[(ci0 + c4) * S_LEN + s] : 0.f;
                pk[c4] = f2bs(v);
            }
            *(short4v*)(RA + (r >> 4) * 2048 + (r & 15) * 8 + cterm) = pk;
        }
    }
    __syncthreads();                               // B0: X + W0 (ds, c1k0)

    // ---- P1: ds (1x1) -> dk regs, AND c1_0 k0 -> acc ; stage c1k1 -> W1
    stage_async<8192>(W1, wq + OFF_L0C1_1, wave, lane);
    zero_acc(acc);
    conv_tap<2>(RA, W0 + wqb2, aoff0, acc, 0);
    #pragma unroll
    for (int mt = 0; mt < 2; ++mt) {
        const int co4 = cobase + mt * 16 + quad * 4;
        const floatx4 bb = *(const floatx4*)(ds_b + co4);
        #pragma unroll
        for (int nt = 0; nt < 3; ++nt) {
            floatx4 y = acc[mt][nt] + bb;
            if (zr[nt]) y = {0.f, 0.f, 0.f, 0.f};
            dk[mt * 3 + nt] = pack4(y);
        }
    }
    mkoff(aoffd, srow, l16, quad, 1);
    zero_acc(acc);
    conv_tap<2>(RA, W0 + 8192 + wqb2, aoffd, acc, 0);
    __syncthreads();                               // B1: c1k1 weights

    // ---- P2: c1_0 k1 -> T into RB ; stage c2k0 -> W0
    stage_async<16384>(W0, wq + OFF_L0C2_0, wave, lane);
    conv_tap<2>(RA, W1 + wqb2, aoff0, acc, 0);
    #pragma unroll
    for (int mt = 0; mt < 2; ++mt) {
        const int co4 = cobase + mt * 16 + quad * 4;
        const floatx4 bb = *(const floatx4*)(b1_0 + co4);
        #pragma unroll
        for (int nt = 0; nt < 3; ++nt) {
            floatx4 y = acc[mt][nt] + bb;
            #pragma unroll
            for (int rr = 0; rr < 4; ++rr) y[rr] = elu_f(y[rr]);
            if (zr[nt]) y = {0.f, 0.f, 0.f, 0.f};
            *(short4v*)(RB + sb[nt] + ct[mt]) = pack4(y);
        }
    }
    __syncthreads();                               // B2: T + c2k0 weights

    // ---- P3: c2_0 k0 (reads RB) ; stage c2k1 -> W1
    stage_async<16384>(W1, wq + OFF_L0C2_1, wave, lane);
    zero_acc(acc);
    conv_tap<4>(RB, W0 + wqb4, aoffd, acc, 0);
    __syncthreads();                               // B3: c2k1 weights

    // ---- P4: c2_0 k1 -> x1 into RA (X dead); res = dk; keep x1
    stage_async<16384>(W0, wq + OFF_C1B, wave, lane);
    conv_tap<4>(RB, W1 + wqb4, aoff0, acc, 0);
    #pragma unroll
    for (int mt = 0; mt < 2; ++mt) {
        const int co4 = cobase + mt * 16 + quad * 4;
        const floatx4 bb = *(const floatx4*)(b2_0 + co4);
        #pragma unroll
        for (int nt = 0; nt < 3; ++nt) {
            floatx4 y = acc[mt][nt] + bb;
            const short4v d4 = dk[mt * 3 + nt];
            #pragma unroll
            for (int rr = 0; rr < 4; ++rr) {
                y[rr] = elu_f(y[rr]);
                y[rr] = elu_f(y[rr] + bs2f(d4[rr]));
            }
            if (zr[nt]) y = {0.f, 0.f, 0.f, 0.f};
            const short4v pk = pack4(y);
            *(short4v*)(RA + sb[nt] + ct[mt]) = pk;
            x1keep[mt * 3 + nt] = pk;
        }
    }
    __syncthreads();                               // B4: x1 + L1 c1k0 weights

    // ---- levels 1..3 (d = 2, 4, 8): io in RA (in-place), T in RB
    const int mc1[3] = {0, 0, 16};   // conv1 output floor per lvl
    const int mc2[3] = {0, 16, 32};  // conv2 output floor per lvl
    #pragma unroll
    for (int lvl = 0; lvl < 3; ++lvl) {
        const int d = 2 << lvl;
        const int n1 = ntfloor(mc1[lvl], srow);
        const int n2 = ntfloor(mc2[lvl], srow);
        mkoff(aoffd, srow, l16, quad, d);
        // c1 k0 (W0), prefetch c1k1 -> W1
        stage_async<16384>(W1, wq + OFF_C1B + lvl * 32768 + 16384, wave, lane);
        zero_acc(acc);
        conv_tap<4>(RA, W0 + wqb4, aoffd, acc, n1);
        __syncthreads();
        // c1 k1 (W1) -> T into RB; prefetch c2k0 -> W0
        stage_async<16384>(W0, wq + OFF_C2B + lvl * 32768, wave, lane);
        conv_tap<4>(RA, W1 + wqb4, aoff0, acc, n1);
        #pragma unroll
        for (int mt = 0; mt < 2; ++mt) {
            const int co4 = cobase + mt * 16 + quad * 4;
            const floatx4 bb = *(const floatx4*)(B1 + lvl * 128 + co4);
            #pragma unroll
            for (int nt = 0; nt < 3; ++nt) {
                if (nt < n1) continue;
                floatx4 y = acc[mt][nt] + bb;
                #pragma unroll
                for (int rr = 0; rr < 4; ++rr) y[rr] = elu_f(y[rr]);
                if (zr[nt]) y = {0.f, 0.f, 0.f, 0.f};
                *(short4v*)(RB + sb[nt] + ct[mt]) = pack4(y);
            }
        }
        __syncthreads();
        // c2 k0 (W0), reads T(RB); prefetch c2k1 -> W1
        stage_async<16384>(W1, wq + OFF_C2B + lvl * 32768 + 16384, wave, lane);
        zero_acc(acc);
        conv_tap<4>(RB, W0 + wqb4, aoffd, acc, n2);
        __syncthreads();
        // c2 k1 (W1) -> out into RA in-place (lane-local res); prefetch next
        stage_async<16384>(W0, wq + OFF_C1B + (lvl + 1) * 32768, wave, lane);
        conv_tap<4>(RB, W1 + wqb4, aoff0, acc, n2);
        #pragma unroll
        for (int mt = 0; mt < 2; ++mt) {
            const int co4 = cobase + mt * 16 + quad * 4;
            const floatx4 bb = *(const floatx4*)(B2 + lvl * 128 + co4);
            #pragma unroll
            for (int nt = 0; nt < 3; ++nt) {
                if (nt < n2) continue;
                short* p = RA + sb[nt] + ct[mt];
                const short4v old = *(const short4v*)p;
                floatx4 y = acc[mt][nt] + bb;
                #pragma unroll
                for (int rr = 0; rr < 4; ++rr) {
                    y[rr] = elu_f(y[rr]);
                    y[rr] = elu_f(y[rr] + bs2f(old[rr]));
                }
                if (zr[nt]) y = {0.f, 0.f, 0.f, 0.f};
                *(short4v*)p = pack4(y);
            }
        }
        __syncthreads();
    }

    // ---- level 4 (d=16): c1 floor 48 (group0 idle), c2 floor 64;
    //      d=16 act-fragment reuse across each conv's k0->k1 phases.
    {
        const int n1 = ntfloor(48, srow);
        const int n2 = ntfloor(64, srow);
        mkoff(aoffd, srow, l16, quad, 16);
        short8 cch[2][4];
        // c1 k0 (W0), cache frags; prefetch c1k1 -> W1
        stage_async<16384>(W1, wq + OFF_C1B + 3 * 32768 + 16384, wave, lane);
        zero_acc(acc);
        conv_tap_cache(RA, W0 + wqb4, aoffd, acc, n1, cch);
        __syncthreads();
        // c1 k1 (W1) -> T into RB (reuse cch); prefetch c2k0 -> W0
        stage_async<16384>(W0, wq + OFF_C2B + 3 * 32768, wave, lane);
        conv_tap_reuse(RA, W1 + wqb4, aoff0, acc, n1, cch);
        #pragma unroll
        for (int mt = 0; mt < 2; ++mt) {
            const int co4 = cobase + mt * 16 + quad * 4;
            const floatx4 bb = *(const floatx4*)(B1 + 384 + co4);
            #pragma unroll
            for (int nt = 0; nt < 3; ++nt) {
                if (nt < n1) continue;
                floatx4 y = acc[mt][nt] + bb;
                #pragma unroll
                for (int rr = 0; rr < 4; ++rr) y[rr] = elu_f(y[rr]);
                if (zr[nt]) y = {0.f, 0.f, 0.f, 0.f};
                *(short4v*)(RB + sb[nt] + ct[mt]) = pack4(y);
            }
        }
        __syncthreads();
        // c2 k0 (W0), reads T(RB), cache frags; prefetch c2k1 -> W1
        stage_async<16384>(W1, wq + OFF_C2B + 3 * 32768 + 16384, wave, lane);
        zero_acc(acc);
        conv_tap_cache(RB, W0 + wqb4, aoffd, acc, n2, cch);
        __syncthreads();
        // c2 k1 (W1) (reuse cch) -> final epilogue, rows 64..191 only
        conv_tap_reuse(RB, W1 + wqb4, aoff0, acc, n2, cch);
        #pragma unroll
        for (int mt = 0; mt < 2; ++mt) {
            const int co4 = cobase + mt * 16 + quad * 4;
            const floatx4 bb = *(const floatx4*)(B2 + 384 + co4);
            #pragma unroll
            for (int nt = 0; nt < 3; ++nt) {
                if (srow + nt * 16 < 64) continue;     // halo rows: no output
                const int sl = srow + nt * 16 + l16;
                const int sg = s0g + sl;
                const short4v res = *(const short4v*)(RA + sb[nt] + ct[mt]);
                const short4v k   = x1keep[mt * 3 + nt];
                #pragma unroll
                for (int rr = 0; rr < 4; ++rr) {
                    float y = elu_f(acc[mt][nt][rr] + bb[rr]);
                    y = elu_f(y + bs2f(res[rr]));
                    y += bs2f(k[rr]);
                    out[((size_t)(b * 128 + co4 + rr)) * S_LEN + sg] = y;
                }
            }
        }
    }
}

// ---------------------------------------------------------------------------
// prep_w, gather-style: each thread owns ONE contiguous short8 chunk of the
// fragment-major weight bank (coalesced writes) and gathers its 8 fp32 inputs.
// Fragment-major index: d = hi*(KC*512) + q*512 + k2*128 + r*8 + c
//   with co = hi*16 + r, ci = q*32 + k2*8 + c.
// ---------------------------------------------------------------------------
__global__ __launch_bounds__(256)
void prep_w(const float* __restrict__ w1_0, const float* __restrict__ w2_0,
            const float* __restrict__ ds_w, const float* __restrict__ W1,
            const float* __restrict__ W2, short* __restrict__ wq)
{
    const int cid = blockIdx.x * 256 + threadIdx.x;
    const long d8 = (long)cid * 8;
    if (d8 >= WQ_TOTAL) return;
    short8 o;

    if (d8 < OFF_L0C1_0) {                         // DS: KC=2, CIN=64, 1 tap
        const int local = (int)d8 - OFF_DS;
        const int hi = local >> 10, q = (local >> 9) & 1;
        const int k2 = (local >> 7) & 3, r = (local >> 3) & 15;
        const int co = hi * 16 + r, cb = q * 32 + k2 * 8;
        #pragma unroll
        for (int j = 0; j < 8; ++j) o[j] = f2bs(ds_w[co * 64 + cb + j]);
    } else if (d8 < OFF_L0C2_0) {                  // L0C1 taps: KC=2, CIN=64
        const int tap = (d8 >= OFF_L0C1_1);
        const int local = (int)d8 - (tap ? OFF_L0C1_1 : OFF_L0C1_0);
        const int hi = local >> 10, q = (local >> 9) & 1;
        const int k2 = (local >> 7) & 3, r = (local >> 3) & 15;
        const int co = hi * 16 + r, cb = q * 32 + k2 * 8;
        #pragma unroll
        for (int j = 0; j < 8; ++j) o[j] = f2bs(w1_0[(co * 64 + cb + j) * 2 + tap]);
    } else if (d8 < OFF_C1B) {                     // L0C2 taps: KC=4, CIN=128
        const int tap = (d8 >= OFF_L0C2_1);
        const int local = (int)d8 - (tap ? OFF_L0C2_1 : OFF_L0C2_0);
        const int hi = local >> 11, q = (local >> 9) & 3;
        const int k2 = (local >> 7) & 3, r = (local >> 3) & 15;
        const int co = hi * 16 + r, cb = q * 32 + k2 * 8;
        #pragma unroll
        for (int j = 0; j < 8; ++j) o[j] = f2bs(w2_0[(co * 128 + cb + j) * 2 + tap]);
    } else if (d8 < OFF_C2B) {                     // C1 banks: 4 lvls x 2 taps
        const int l2 = (int)d8 - OFF_C1B;
        const int li = l2 >> 15, tap = (l2 >> 14) & 1, local = l2 & 16383;
        const int hi = local >> 11, q = (local >> 9) & 3;
        const int k2 = (local >> 7) & 3, r = (local >> 3) & 15;
        const int co = hi * 16 + r, cb = q * 32 + k2 * 8;
        const float* src = W1 + (size_t)li * 16384 * 2;
        #pragma unroll
        for (int j = 0; j < 8; ++j) o[j] = f2bs(src[(co * 128 + cb + j) * 2 + tap]);
    } else {                                       // C2 banks
        const int l2 = (int)d8 - OFF_C2B;
        const int li = l2 >> 15, tap = (l2 >> 14) & 1, local = l2 & 16383;
        const int hi = local >> 11, q = (local >> 9) & 3;
        const int k2 = (local >> 7) & 3, r = (local >> 3) & 15;
        const int co = hi * 16 + r, cb = q * 32 + k2 * 8;
        const float* src = W2 + (size_t)li * 16384 * 2;
        #pragma unroll
        for (int j = 0; j < 8; ++j) o[j] = f2bs(src[(co * 128 + cb + j) * 2 + tap]);
    }
    *(short8*)(wq + d8) = o;
}

// ---------------------------------------------------------------------------
extern "C" void kernel_launch(void* const* d_in, const int* in_sizes, int n_in,
                              void* d_out, int out_size, void* d_ws, size_t ws_size,
                              hipStream_t stream) {
    const float* x_in = (const float*)d_in[0];
    const float* w1_0 = (const float*)d_in[1];
    const float* b1_0 = (const float*)d_in[2];
    const float* w2_0 = (const float*)d_in[3];
    const float* b2_0 = (const float*)d_in[4];
    const float* ds_w = (const float*)d_in[5];
    const float* ds_b = (const float*)d_in[6];
    const float* W1   = (const float*)d_in[7];
    const float* B1   = (const float*)d_in[8];
    const float* W2   = (const float*)d_in[9];
    const float* B2   = (const float*)d_in[10];
    float* out = (float*)d_out;

    short* wq = (short*)d_ws;   // 624 KB fragment-major weight bank

    (void)hipFuncSetAttribute((const void*)tcn_fused,
                              hipFuncAttributeMaxDynamicSharedMemorySize, LDS_BYTES);

    prep_w<<<dim3((WQ_TOTAL / 8 + 255) / 256), 256, 0, stream>>>(
        w1_0, w2_0, ds_w, W1, W2, wq);
    tcn_fused<<<dim3(32, 16), dim3(1024), LDS_BYTES, stream>>>(
        x_in, wq, b1_0, b2_0, ds_b, B1, B2, out);
}

// Round 9
// 166.003 us; speedup vs baseline: 1.0407x; 1.0407x over previous
//
#include <hip/hip_runtime.h>
#include <hip/hip_bf16.h>
#include <math.h>

// Fully-fused TCN, R18: recovery — validated-components-only composition.
// R17's stride-4 interleaved ownership FAILED post-timing (replay-dependent
// output => a stale/unwritten-LDS read introduced by the remap; could not be
// pinned by inspection -> reverted). This kernel = R15's proven dataflow
// (contiguous row-groups + ntfloor dead-row skips + dk-in-regs + merged
// ds/c1k0 phase + fragment-major LDS + async weight double-buffer)
// MINUS setprio (R16 evidence: lockstep regime, cost MfmaUtil 25.4->23.1)
// PLUS R16's coalesced gather-style prep_w. No cch cache (R16 spill).
// LDS = 2x(192x128) act + 2x(128x128) weights = 163840 B (160 KiB), 16 waves.

typedef __attribute__((ext_vector_type(8))) short short8;
typedef __attribute__((ext_vector_type(4))) short short4v;
typedef __attribute__((ext_vector_type(4))) float floatx4;

#define S_LEN 4096
#define ROWS 192                   // 64 halo + 128 outputs (12 row-blocks)
#define AREG (ROWS * 128)          // 24576 shorts per activation region
#define WBUF (128 * 128)           // 16384 shorts per weight buffer (32 KB)
#define LDS_BYTES ((2 * AREG + 2 * WBUF) * 2)   // 163840 B

// weight bank offsets (shorts) — each tap contiguous, fragment-major tiled
#define OFF_DS     0
#define OFF_L0C1_0 8192
#define OFF_L0C1_1 16384
#define OFF_L0C2_0 24576
#define OFF_L0C2_1 40960
#define OFF_C1B    57344      // + lvl*32768 ; tap1 at +16384
#define OFF_C2B    188416     // + lvl*32768 ; tap1 at +16384
#define WQ_TOTAL   319488

__device__ __forceinline__ float elu_f(float v) {
    return v > 0.0f ? v : (__expf(v) - 1.0f);
}
__device__ __forceinline__ short f2bs(float v) {
    __hip_bfloat16 h = __float2bfloat16(v);
    return *reinterpret_cast<short*>(&h);
}
__device__ __forceinline__ float bs2f(short s) {
    __hip_bfloat16 h = *reinterpret_cast<__hip_bfloat16*>(&s);
    return __bfloat162float(h);
}
__device__ __forceinline__ short4v pack4(const floatx4 v) {
    __hip_bfloat162 p0 = __float22bfloat162_rn(make_float2(v[0], v[1]));
    __hip_bfloat162 p1 = __float22bfloat162_rn(make_float2(v[2], v[3]));
    short4v r;
    r[0] = ((const short*)&p0)[0]; r[1] = ((const short*)&p0)[1];
    r[2] = ((const short*)&p1)[0]; r[3] = ((const short*)&p1)[1];
    return r;
}

// async 16B global->LDS copy (wave-uniform LDS base + lane*16 hardware rule)
__device__ __forceinline__ void gld_lds16(const void* g, void* l) {
    __builtin_amdgcn_global_load_lds(
        (const __attribute__((address_space(1))) void*)g,
        (__attribute__((address_space(3))) void*)l, 16, 0, 0);
}

// Issue async loads of one pre-tiled weight tap (NSH shorts) into LDS.
template<int NSH>
__device__ __forceinline__ void stage_async(short* __restrict__ lds,
                                            const short* __restrict__ src,
                                            int wave, int lane)
{
    constexpr int NI = (NSH * 2) / 16384;  // insts per wave (1 KB each, 16 waves)
    const char* g = (const char*)src + wave * 1024 + lane * 16;
    char* l = (char*)lds + wave * 1024;    // wave-uniform base
    #pragma unroll
    for (int i = 0; i < NI; ++i)
        gld_lds16(g + i * 16384, l + i * 16384);
}

// activation fragment offsets for one dilation (per nt), clamped at row 0
__device__ __forceinline__ void mkoff(int (&o)[3], int srow, int l16, int quad, int d) {
    #pragma unroll
    for (int nt = 0; nt < 3; ++nt) {
        int r = srow + nt * 16 + l16 - d;
        if (r < 0) r = 0;              // clamped rows never feed valid outputs
        o[nt] = (r >> 4) * 2048 + (r & 15) * 8 + quad * 128;
    }
}

// nt0 = first needed nt for this wave given a row floor (scalar math)
__device__ __forceinline__ int ntfloor(int minrow, int srow) {
    return (minrow > srow) ? ((minrow - srow + 15) >> 4) : 0;
}

// ---------------------------------------------------------------------------
// One tap's MFMAs: acc[mt][nt] += W[co][ci] * X[r - d][ci], nt >= nt0 only.
// ---------------------------------------------------------------------------
template<int KCH>
__device__ __forceinline__ void conv_tap(const short* __restrict__ Lin,
                                         const short* __restrict__ Lw,
                                         const int (&ao)[3], floatx4 (&acc)[2][3],
                                         const int nt0)
{
    if (nt0 >= 3) return;                  // whole wave idle this tap
    short8 wf[2][KCH];
    #pragma unroll
    for (int mt = 0; mt < 2; ++mt)
        #pragma unroll
        for (int kc = 0; kc < KCH; ++kc)
            wf[mt][kc] = *(const short8*)(Lw + mt * (KCH * 512) + kc * 512);
    #pragma unroll
    for (int nt = 0; nt < 3; ++nt) {
        if (nt < nt0) continue;
        const short* ab = Lin + ao[nt];
        #pragma unroll
        for (int kc = 0; kc < KCH; ++kc) {
            const short8 bf = *(const short8*)(ab + kc * 512);
            #pragma unroll
            for (int mt = 0; mt < 2; ++mt)
                acc[mt][nt] = __builtin_amdgcn_mfma_f32_16x16x32_bf16(wf[mt][kc], bf, acc[mt][nt], 0, 0, 0);
        }
    }
}

__device__ __forceinline__ void zero_acc(floatx4 (&acc)[2][3]) {
    #pragma unroll
    for (int mt = 0; mt < 2; ++mt)
        #pragma unroll
        for (int nt = 0; nt < 3; ++nt) acc[mt][nt] = {0.f, 0.f, 0.f, 0.f};
}

// ---------------------------------------------------------------------------
__global__ __launch_bounds__(1024, 4)
void tcn_fused(const float* __restrict__ x,     // fp32 [16,64,4096] channel-first
               const short* __restrict__ wq,
               const float* __restrict__ b1_0, const float* __restrict__ b2_0,
               const float* __restrict__ ds_b, const float* __restrict__ B1,
               const float* __restrict__ B2, float* __restrict__ out)
{
    extern __shared__ short L[];
    short* RA = L;                 // level io (X, then x1, ... in-place)
    short* RB = L + AREG;          // T scratch
    short* W0 = L + 2 * AREG;      // weight double-buffer
    short* W1 = L + 2 * AREG + WBUF;

    const int tid  = threadIdx.x;
    const int wave = __builtin_amdgcn_readfirstlane(tid >> 6);   // scalar
    const int lane = tid & 63;
    const int l16  = lane & 15, quad = lane >> 4;
    const int cobase = (wave & 3) * 32;    // 4 co-groups of 32   (scalar)
    const int srow   = (wave >> 2) * 48;   // 4 row-groups of 48  (scalar)
    const int s0  = blockIdx.x * 128;
    const int s0g = s0 - 64;
    const int b   = blockIdx.y;
    const bool zb = (s0 == 0);             // zero rows with global s < 0

    // per-wave constant addressing
    const int wqb2 = (cobase >> 4) * 1024 + quad * 128 + l16 * 8;  // KCH=2 base
    const int wqb4 = (cobase >> 4) * 2048 + quad * 128 + l16 * 8;  // KCH=4 base
    int aoff0[3], aoffd[3];
    mkoff(aoff0, srow, l16, quad, 0);
    int sb[3];
    #pragma unroll
    for (int nt = 0; nt < 3; ++nt) {
        const int sl = srow + nt * 16 + l16;
        sb[nt] = (sl >> 4) * 2048 + (sl & 15) * 8;
    }
    int ct[2];
    #pragma unroll
    for (int mt = 0; mt < 2; ++mt) {
        const int co4 = cobase + mt * 16 + quad * 4;
        ct[mt] = (co4 >> 5) * 512 + ((co4 >> 3) & 3) * 128 + (co4 & 7);
    }
    // uniform halo-zero flags per nt (srow + nt*16 is a multiple of 16)
    bool zr[3];
    #pragma unroll
    for (int nt = 0; nt < 3; ++nt) zr[nt] = zb && (srow + nt * 16 < 64);

    floatx4 acc[2][3];
    short4v x1keep[6];
    short4v dk[6];

    // ---- prologue: stage ds + c1_0k0 (both 16KB) into W0; stage X into RA
    stage_async<8192>(W0, wq + OFF_DS, wave, lane);
    stage_async<8192>(W0 + 8192, wq + OFF_L0C1_0, wave, lane);
    {
        const float* xp = x + (size_t)b * 64 * S_LEN;
        const int ci0 = wave * 4;
        const int cterm = (ci0 >> 5) * 512 + ((ci0 >> 3) & 3) * 128 + (ci0 & 7);
        #pragma unroll
        for (int h = 0; h < 3; ++h) {
            const int r = lane + h * 64;
            const int s = s0g + r;
            short4v pk;
            #pragma unroll
            for (int c4 = 0; c4 < 4; ++c4) {
                const float v = (s >= 0) ? xp[(ci0 + c4) * S_LEN + s] : 0.f;
                pk[c4] = f2bs(v);
            }
            *(short4v*)(RA + (r >> 4) * 2048 + (r & 15) * 8 + cterm) = pk;
        }
    }
    __syncthreads();                               // B0: X + W0 (ds, c1k0)

    // ---- P1: ds (1x1) -> dk regs, AND c1_0 k0 -> acc ; stage c1k1 -> W1
    stage_async<8192>(W1, wq + OFF_L0C1_1, wave, lane);
    zero_acc(acc);
    conv_tap<2>(RA, W0 + wqb2, aoff0, acc, 0);
    #pragma unroll
    for (int mt = 0; mt < 2; ++mt) {
        const int co4 = cobase + mt * 16 + quad * 4;
        const floatx4 bb = *(const floatx4*)(ds_b + co4);
        #pragma unroll
        for (int nt = 0; nt < 3; ++nt) {
            floatx4 y = acc[mt][nt] + bb;
            if (zr[nt]) y = {0.f, 0.f, 0.f, 0.f};
            dk[mt * 3 + nt] = pack4(y);
        }
    }
    mkoff(aoffd, srow, l16, quad, 1);
    zero_acc(acc);
    conv_tap<2>(RA, W0 + 8192 + wqb2, aoffd, acc, 0);
    __syncthreads();                               // B1: c1k1 weights

    // ---- P2: c1_0 k1 -> T into RB ; stage c2k0 -> W0
    stage_async<16384>(W0, wq + OFF_L0C2_0, wave, lane);
    conv_tap<2>(RA, W1 + wqb2, aoff0, acc, 0);
    #pragma unroll
    for (int mt = 0; mt < 2; ++mt) {
        const int co4 = cobase + mt * 16 + quad * 4;
        const floatx4 bb = *(const floatx4*)(b1_0 + co4);
        #pragma unroll
        for (int nt = 0; nt < 3; ++nt) {
            floatx4 y = acc[mt][nt] + bb;
            #pragma unroll
            for (int rr = 0; rr < 4; ++rr) y[rr] = elu_f(y[rr]);
            if (zr[nt]) y = {0.f, 0.f, 0.f, 0.f};
            *(short4v*)(RB + sb[nt] + ct[mt]) = pack4(y);
        }
    }
    __syncthreads();                               // B2: T + c2k0 weights

    // ---- P3: c2_0 k0 (reads RB) ; stage c2k1 -> W1
    stage_async<16384>(W1, wq + OFF_L0C2_1, wave, lane);
    zero_acc(acc);
    conv_tap<4>(RB, W0 + wqb4, aoffd, acc, 0);
    __syncthreads();                               // B3: c2k1 weights

    // ---- P4: c2_0 k1 -> x1 into RA (X dead); res = dk; keep x1
    stage_async<16384>(W0, wq + OFF_C1B, wave, lane);
    conv_tap<4>(RB, W1 + wqb4, aoff0, acc, 0);
    #pragma unroll
    for (int mt = 0; mt < 2; ++mt) {
        const int co4 = cobase + mt * 16 + quad * 4;
        const floatx4 bb = *(const floatx4*)(b2_0 + co4);
        #pragma unroll
        for (int nt = 0; nt < 3; ++nt) {
            floatx4 y = acc[mt][nt] + bb;
            const short4v d4 = dk[mt * 3 + nt];
            #pragma unroll
            for (int rr = 0; rr < 4; ++rr) {
                y[rr] = elu_f(y[rr]);
                y[rr] = elu_f(y[rr] + bs2f(d4[rr]));
            }
            if (zr[nt]) y = {0.f, 0.f, 0.f, 0.f};
            const short4v pk = pack4(y);
            *(short4v*)(RA + sb[nt] + ct[mt]) = pk;
            x1keep[mt * 3 + nt] = pk;
        }
    }
    __syncthreads();                               // B4: x1 + L1 c1k0 weights

    // ---- levels 1..3 (d = 2, 4, 8): io in RA (in-place), T in RB
    // backward row requirements (16-row granularity):
    const int mc1[3] = {0, 0, 16};   // conv1 output floor per lvl
    const int mc2[3] = {0, 16, 32};  // conv2 output floor per lvl
    #pragma unroll
    for (int lvl = 0; lvl < 3; ++lvl) {
        const int d = 2 << lvl;
        const int n1 = ntfloor(mc1[lvl], srow);
        const int n2 = ntfloor(mc2[lvl], srow);
        mkoff(aoffd, srow, l16, quad, d);
        // c1 k0 (W0), prefetch c1k1 -> W1
        stage_async<16384>(W1, wq + OFF_C1B + lvl * 32768 + 16384, wave, lane);
        zero_acc(acc);
        conv_tap<4>(RA, W0 + wqb4, aoffd, acc, n1);
        __syncthreads();
        // c1 k1 (W1) -> T into RB; prefetch c2k0 -> W0
        stage_async<16384>(W0, wq + OFF_C2B + lvl * 32768, wave, lane);
        conv_tap<4>(RA, W1 + wqb4, aoff0, acc, n1);
        #pragma unroll
        for (int mt = 0; mt < 2; ++mt) {
            const int co4 = cobase + mt * 16 + quad * 4;
            const floatx4 bb = *(const floatx4*)(B1 + lvl * 128 + co4);
            #pragma unroll
            for (int nt = 0; nt < 3; ++nt) {
                if (nt < n1) continue;
                floatx4 y = acc[mt][nt] + bb;
                #pragma unroll
                for (int rr = 0; rr < 4; ++rr) y[rr] = elu_f(y[rr]);
                if (zr[nt]) y = {0.f, 0.f, 0.f, 0.f};
                *(short4v*)(RB + sb[nt] + ct[mt]) = pack4(y);
            }
        }
        __syncthreads();
        // c2 k0 (W0), reads T(RB); prefetch c2k1 -> W1
        stage_async<16384>(W1, wq + OFF_C2B + lvl * 32768 + 16384, wave, lane);
        zero_acc(acc);
        conv_tap<4>(RB, W0 + wqb4, aoffd, acc, n2);
        __syncthreads();
        // c2 k1 (W1) -> out into RA in-place (lane-local res); prefetch next
        stage_async<16384>(W0, wq + OFF_C1B + (lvl + 1) * 32768, wave, lane);
        conv_tap<4>(RB, W1 + wqb4, aoff0, acc, n2);
        #pragma unroll
        for (int mt = 0; mt < 2; ++mt) {
            const int co4 = cobase + mt * 16 + quad * 4;
            const floatx4 bb = *(const floatx4*)(B2 + lvl * 128 + co4);
            #pragma unroll
            for (int nt = 0; nt < 3; ++nt) {
                if (nt < n2) continue;
                short* p = RA + sb[nt] + ct[mt];
                const short4v old = *(const short4v*)p;
                floatx4 y = acc[mt][nt] + bb;
                #pragma unroll
                for (int rr = 0; rr < 4; ++rr) {
                    y[rr] = elu_f(y[rr]);
                    y[rr] = elu_f(y[rr] + bs2f(old[rr]));
                }
                if (zr[nt]) y = {0.f, 0.f, 0.f, 0.f};
                *(short4v*)p = pack4(y);
            }
        }
        __syncthreads();
    }

    // ---- level 4 (d=16): c1 floor 48 (group0 idle), c2 floor 64
    {
        const int n1 = ntfloor(48, srow);
        const int n2 = ntfloor(64, srow);
        mkoff(aoffd, srow, l16, quad, 16);
        // c1 k0 (W0), prefetch c1k1 -> W1
        stage_async<16384>(W1, wq + OFF_C1B + 3 * 32768 + 16384, wave, lane);
        zero_acc(acc);
        conv_tap<4>(RA, W0 + wqb4, aoffd, acc, n1);
        __syncthreads();
        // c1 k1 (W1) -> T into RB; prefetch c2k0 -> W0
        stage_async<16384>(W0, wq + OFF_C2B + 3 * 32768, wave, lane);
        conv_tap<4>(RA, W1 + wqb4, aoff0, acc, n1);
        #pragma unroll
        for (int mt = 0; mt < 2; ++mt) {
            const int co4 = cobase + mt * 16 + quad * 4;
            const floatx4 bb = *(const floatx4*)(B1 + 384 + co4);
            #pragma unroll
            for (int nt = 0; nt < 3; ++nt) {
                if (nt < n1) continue;
                floatx4 y = acc[mt][nt] + bb;
                #pragma unroll
                for (int rr = 0; rr < 4; ++rr) y[rr] = elu_f(y[rr]);
                if (zr[nt]) y = {0.f, 0.f, 0.f, 0.f};
                *(short4v*)(RB + sb[nt] + ct[mt]) = pack4(y);
            }
        }
        __syncthreads();
        // c2 k0 (W0), reads T(RB); prefetch c2k1 -> W1
        stage_async<16384>(W1, wq + OFF_C2B + 3 * 32768 + 16384, wave, lane);
        zero_acc(acc);
        conv_tap<4>(RB, W0 + wqb4, aoffd, acc, n2);
        __syncthreads();
        // c2 k1 (W1) -> final epilogue, rows 64..191 only; res = RA; + x1keep
        conv_tap<4>(RB, W1 + wqb4, aoff0, acc, n2);
        #pragma unroll
        for (int mt = 0; mt < 2; ++mt) {
            const int co4 = cobase + mt * 16 + quad * 4;
            const floatx4 bb = *(const floatx4*)(B2 + 384 + co4);
            #pragma unroll
            for (int nt = 0; nt < 3; ++nt) {
                if (srow + nt * 16 < 64) continue;     // halo rows: no output
                const int sl = srow + nt * 16 + l16;
                const int sg = s0g + sl;
                const short4v res = *(const short4v*)(RA + sb[nt] + ct[mt]);
                const short4v k   = x1keep[mt * 3 + nt];
                #pragma unroll
                for (int rr = 0; rr < 4; ++rr) {
                    float y = elu_f(acc[mt][nt][rr] + bb[rr]);
                    y = elu_f(y + bs2f(res[rr]));
                    y += bs2f(k[rr]);
                    out[((size_t)(b * 128 + co4 + rr)) * S_LEN + sg] = y;
                }
            }
        }
    }
}

// ---------------------------------------------------------------------------
// prep_w, gather-style: each thread owns ONE contiguous short8 chunk of the
// fragment-major weight bank (coalesced writes) and gathers its 8 fp32 inputs.
// Fragment-major index: d = hi*(KC*512) + q*512 + k2*128 + r*8 + c
//   with co = hi*16 + r, ci = q*32 + k2*8 + c.
// ---------------------------------------------------------------------------
__global__ __launch_bounds__(256)
void prep_w(const float* __restrict__ w1_0, const float* __restrict__ w2_0,
            const float* __restrict__ ds_w, const float* __restrict__ W1,
            const float* __restrict__ W2, short* __restrict__ wq)
{
    const int cid = blockIdx.x * 256 + threadIdx.x;
    const long d8 = (long)cid * 8;
    if (d8 >= WQ_TOTAL) return;
    short8 o;

    if (d8 < OFF_L0C1_0) {                         // DS: KC=2, CIN=64, 1 tap
        const int local = (int)d8 - OFF_DS;
        const int hi = local >> 10, q = (local >> 9) & 1;
        const int k2 = (local >> 7) & 3, r = (local >> 3) & 15;
        const int co = hi * 16 + r, cb = q * 32 + k2 * 8;
        #pragma unroll
        for (int j = 0; j < 8; ++j) o[j] = f2bs(ds_w[co * 64 + cb + j]);
    } else if (d8 < OFF_L0C2_0) {                  // L0C1 taps: KC=2, CIN=64
        const int tap = (d8 >= OFF_L0C1_1);
        const int local = (int)d8 - (tap ? OFF_L0C1_1 : OFF_L0C1_0);
        const int hi = local >> 10, q = (local >> 9) & 1;
        const int k2 = (local >> 7) & 3, r = (local >> 3) & 15;
        const int co = hi * 16 + r, cb = q * 32 + k2 * 8;
        #pragma unroll
        for (int j = 0; j < 8; ++j) o[j] = f2bs(w1_0[(co * 64 + cb + j) * 2 + tap]);
    } else if (d8 < OFF_C1B) {                     // L0C2 taps: KC=4, CIN=128
        const int tap = (d8 >= OFF_L0C2_1);
        const int local = (int)d8 - (tap ? OFF_L0C2_1 : OFF_L0C2_0);
        const int hi = local >> 11, q = (local >> 9) & 3;
        const int k2 = (local >> 7) & 3, r = (local >> 3) & 15;
        const int co = hi * 16 + r, cb = q * 32 + k2 * 8;
        #pragma unroll
        for (int j = 0; j < 8; ++j) o[j] = f2bs(w2_0[(co * 128 + cb + j) * 2 + tap]);
    } else if (d8 < OFF_C2B) {                     // C1 banks: 4 lvls x 2 taps
        const int l2 = (int)d8 - OFF_C1B;
        const int li = l2 >> 15, tap = (l2 >> 14) & 1, local = l2 & 16383;
        const int hi = local >> 11, q = (local >> 9) & 3;
        const int k2 = (local >> 7) & 3, r = (local >> 3) & 15;
        const int co = hi * 16 + r, cb = q * 32 + k2 * 8;
        const float* src = W1 + (size_t)li * 16384 * 2;
        #pragma unroll
        for (int j = 0; j < 8; ++j) o[j] = f2bs(src[(co * 128 + cb + j) * 2 + tap]);
    } else {                                       // C2 banks
        const int l2 = (int)d8 - OFF_C2B;
        const int li = l2 >> 15, tap = (l2 >> 14) & 1, local = l2 & 16383;
        const int hi = local >> 11, q = (local >> 9) & 3;
        const int k2 = (local >> 7) & 3, r = (local >> 3) & 15;
        const int co = hi * 16 + r, cb = q * 32 + k2 * 8;
        const float* src = W2 + (size_t)li * 16384 * 2;
        #pragma unroll
        for (int j = 0; j < 8; ++j) o[j] = f2bs(src[(co * 128 + cb + j) * 2 + tap]);
    }
    *(short8*)(wq + d8) = o;
}

// ---------------------------------------------------------------------------
extern "C" void kernel_launch(void* const* d_in, const int* in_sizes, int n_in,
                              void* d_out, int out_size, void* d_ws, size_t ws_size,
                              hipStream_t stream) {
    const float* x_in = (const float*)d_in[0];
    const float* w1_0 = (const float*)d_in[1];
    const float* b1_0 = (const float*)d_in[2];
    const float* w2_0 = (const float*)d_in[3];
    const float* b2_0 = (const float*)d_in[4];
    const float* ds_w = (const float*)d_in[5];
    const float* ds_b = (const float*)d_in[6];
    const float* W1   = (const float*)d_in[7];
    const float* B1   = (const float*)d_in[8];
    const float* W2   = (const float*)d_in[9];
    const float* B2   = (const float*)d_in[10];
    float* out = (float*)d_out;

    short* wq = (short*)d_ws;   // 624 KB fragment-major weight bank

    (void)hipFuncSetAttribute((const void*)tcn_fused,
                              hipFuncAttributeMaxDynamicSharedMemorySize, LDS_BYTES);

    prep_w<<<dim3((WQ_TOTAL / 8 + 255) / 256), 256, 0, stream>>>(
        w1_0, w2_0, ds_w, W1, W2, wq);
    tcn_fused<<<dim3(32, 16), dim3(1024), LDS_BYTES, stream>>>(
        x_in, wq, b1_0, b2_0, ds_b, B1, B2, out);
}